// Round 11
// baseline (258.780 us; speedup 1.0000x reference)
//
#include <hip/hip_runtime.h>

#define NUM_HEADS 16
#define HEAD_DIM  64
#define EMB       1024
#define SEQ       2048
#define BATCH     4
#define MROWS     (BATCH * SEQ)          // 8192
#define QKV_ELEMS (MROWS * EMB)          // 8388608

typedef __attribute__((ext_vector_type(4)))  float  floatx4;
typedef __attribute__((ext_vector_type(16))) float  floatx16;
typedef __attribute__((ext_vector_type(8)))  __bf16 bf16x8;

__device__ __forceinline__ unsigned short f2bf(float f) {
    unsigned int u = __float_as_uint(f);
    u += 0x7fffu + ((u >> 16) & 1u);
    return (unsigned short)(u >> 16);
}

__device__ __forceinline__ ushort4 pk4(float4 v) {
    return make_ushort4(f2bf(v.x), f2bf(v.y), f2bf(v.z), f2bf(v.w));
}

// pack 4 fp32 -> 4 bf16 (TRUNCATING) in 2 uints via v_perm_b32.
// P feeds the numerator (P@V); the denominator is summed from the SAME
// truncated values in fp32 (see dsum below), so the one-sided truncation
// bias cancels in O/l exactly as with the old ones-MFMA.
__device__ __forceinline__ uint2 packbf4t(float a0, float a1, float a2, float a3) {
    uint2 r;
    r.x = __builtin_amdgcn_perm(__float_as_uint(a1), __float_as_uint(a0), 0x07060302u);
    r.y = __builtin_amdgcn_perm(__float_as_uint(a3), __float_as_uint(a2), 0x07060302u);
    return r;
}

__device__ __forceinline__ bf16x8 mk8(uint2 lo, uint2 hi) {
    union { uint4 u; bf16x8 b; } cvt;
    cvt.u = make_uint4(lo.x, lo.y, hi.x, hi.y);
    return cvt.b;
}

// truncate f32 to bf16 precision (round-toward-zero), stay in f32
__device__ __forceinline__ float truncbf(float f) {
    return __uint_as_float(__float_as_uint(f) & 0xffff0000u);
}

#define MFMA16(a, b, c) __builtin_amdgcn_mfma_f32_16x16x32_bf16((a), (b), (c), 0, 0, 0)
#define MFMA32(a, b, c) __builtin_amdgcn_mfma_f32_32x32x16_bf16((a), (b), (c), 0, 0, 0)
#define EXP2(x) __builtin_amdgcn_exp2f(x)

// raw barrier (no compiler-inserted vmcnt(0) drain) + compiler memory fence
#define BAR() asm volatile("s_barrier" ::: "memory")

// async global->LDS, 16B per lane; LDS dest = wave-uniform base + lane*16
__device__ __forceinline__ void async16(const unsigned short* g, unsigned short* l) {
    __builtin_amdgcn_global_load_lds((const __attribute__((address_space(1))) void*)g,
                                     (__attribute__((address_space(3))) void*)l,
                                     16, 0, 0);
}

// Bank-conflict-killing chunk rotation for [N][32] DMA tiles:
// row R's four 16B chunks are stored rotated by (R>>1)&3. Staging lane i
// (R = base + (i>>2), base % 8 == 0) fetches LOGICAL chunk
// ((i&3) - ((i>>3)&3)) & 3; readers use phys chunk (C + ((R>>1)&3)) & 3.

// q scale folded with log2(e): 0.125 * 1.4426950408889634
#define QSCALE 0.18033688011112042f

// --- attn inner-loop macros (expand in-scope; no lambdas — round-5's spill
// was the by-ref lambda + conditional assign forcing scratch, NOT pressure:
// VGPR was 64 with 141MB scratch traffic) ---
// QK^T for 32-kv tile ttc into dst: 4 chained MFMA32. Uses S/qf/l31/hl/rrot.
#define QK_TILE(dst, ttc) do {                                                \
    _Pragma("unroll")                                                         \
    for (int i_ = 0; i_ < 16; ++i_) (dst)[i_] = 0.f;                          \
    _Pragma("unroll")                                                         \
    for (int ks_ = 0; ks_ < 4; ++ks_) {                                       \
        bf16x8 kf_ = *(const bf16x8*)&S[(ks_ >> 1) * 4096 +                   \
                     ((ttc) * 32 + l31) * 32 +                                \
                     ((((ks_ & 1) * 2 + hl) + rrot) & 3) * 8];                \
        (dst) = MFMA32(kf_, qf[ks_], (dst));                                  \
    }                                                                         \
} while (0)

// dsum (same tree as verified rounds 3-10) + truncating pack + permlane
// C->A exchange + PV MFMAs for tile ttc. Uses S/hl/l31/rrot/dsum/o.
#define SM_PV(ev, ttc) do {                                                   \
    {                                                                         \
        float t0  = truncbf(ev[0]),  t1  = truncbf(ev[1]);                    \
        float t2  = truncbf(ev[2]),  t3  = truncbf(ev[3]);                    \
        float t4  = truncbf(ev[4]),  t5  = truncbf(ev[5]);                    \
        float t6  = truncbf(ev[6]),  t7  = truncbf(ev[7]);                    \
        float t8  = truncbf(ev[8]),  t9  = truncbf(ev[9]);                    \
        float t10 = truncbf(ev[10]), t11 = truncbf(ev[11]);                   \
        float t12 = truncbf(ev[12]), t13 = truncbf(ev[13]);                   \
        float t14 = truncbf(ev[14]), t15 = truncbf(ev[15]);                   \
        dsum += (((t0 + t1) + (t2 + t3)) + ((t4 + t5) + (t6 + t7))) +         \
                (((t8 + t9) + (t10 + t11)) + ((t12 + t13) + (t14 + t15)));    \
    }                                                                         \
    uint2 pk0 = packbf4t(ev[0],  ev[1],  ev[2],  ev[3]);                      \
    uint2 pk1 = packbf4t(ev[4],  ev[5],  ev[6],  ev[7]);                      \
    uint2 pk2 = packbf4t(ev[8],  ev[9],  ev[10], ev[11]);                     \
    uint2 pk3 = packbf4t(ev[12], ev[13], ev[14], ev[15]);                     \
    auto sw0 = __builtin_amdgcn_permlane32_swap(pk0.x, pk1.x, false, false);  \
    auto sw1 = __builtin_amdgcn_permlane32_swap(pk0.y, pk1.y, false, false);  \
    auto sw2 = __builtin_amdgcn_permlane32_swap(pk2.x, pk3.x, false, false);  \
    auto sw3 = __builtin_amdgcn_permlane32_swap(pk2.y, pk3.y, false, false);  \
    bf16x8 pfA = mk8(make_uint2(sw0[0], sw1[0]), make_uint2(sw0[1], sw1[1])); \
    bf16x8 pfB = mk8(make_uint2(sw2[0], sw3[0]), make_uint2(sw2[1], sw3[1])); \
    __builtin_amdgcn_s_setprio(1);                                            \
    _Pragma("unroll")                                                         \
    for (int s_ = 0; s_ < 2; ++s_) {                                          \
        const bf16x8 pf_ = s_ ? pfB : pfA;                                    \
        const int kvblk_ = (ttc) * 2 + s_;                                    \
        const int vbase_ = 8192 + (kvblk_ >> 1) * 2048;                       \
        const int vchun_ = ((((kvblk_ & 1) * 2 + hl) + rrot) & 3) * 8;        \
        _Pragma("unroll")                                                     \
        for (int dt_ = 0; dt_ < 2; ++dt_) {                                   \
            bf16x8 vf_ = *(const bf16x8*)&S[vbase_ + (dt_ * 32 + l31) * 32 + vchun_]; \
            o[dt_] = MFMA32(pf_, vf_, o[dt_]);                                \
        }                                                                     \
    }                                                                         \
    __builtin_amdgcn_s_setprio(0);                                            \
} while (0)

// ---------------------------------------------------------------------------
// Kernel 0: fp32 -> bf16 conversion of x, qkv_w, fc_w (memory-bound pre-pass)
// ---------------------------------------------------------------------------
#define XV4  2097152   // 8388608/4
#define QWV4 786432    // 3145728/4
#define FWV4 262144    // 1048576/4

__global__ __launch_bounds__(256)
void convert_kernel(const float* __restrict__ x, const float* __restrict__ qw,
                    const float* __restrict__ fw,
                    unsigned short* __restrict__ xb, unsigned short* __restrict__ qwb,
                    unsigned short* __restrict__ fwb)
{
    const size_t i = (size_t)blockIdx.x * 256 + threadIdx.x;   // float4 units
    const float* src; unsigned short* dst; size_t off;
    if (i < XV4)              { src = x;  dst = xb;  off = i; }
    else if (i < XV4 + QWV4)  { src = qw; dst = qwb; off = i - XV4; }
    else                      { src = fw; dst = fwb; off = i - (XV4 + QWV4); }
    float4 v = ((const float4*)src)[off];
    ((ushort4*)dst)[off] = pk4(v);
}

// ---------------------------------------------------------------------------
// Kernel 1: qkv = xb @ qkv_w^T + qkv_b  (all-bf16, rot-swizzled LDS)
// -> Q (scaled,[b,h,n,d]), K ([b,h,n,d]), V^T ([b,h,d,n]); bf16
// Round-10 VERIFIED (+5.7us total): round-4 structure with BK=64 — K-slab
// as TWO [128][32] halves; halves the barrier/drain events (32 -> 16
// iters, m233: drain is ~72% of the 2-phase loop). LDS 32KB, 3 blocks/CU.
// ---------------------------------------------------------------------------
__global__ __launch_bounds__(256, 3)
void qkv_kernel(const unsigned short* __restrict__ X, const unsigned short* __restrict__ W,
                const float* __restrict__ BIAS,
                unsigned short* __restrict__ qb, unsigned short* __restrict__ kb,
                unsigned short* __restrict__ vtb)
{
    __shared__ unsigned short As[2][128 * 32];   // two k-halves, 16 KB
    __shared__ unsigned short Bs[2][128 * 32];   // 16 KB

    const int t    = threadIdx.x;
    const int n0   = blockIdx.x * 128;
    const int m0   = blockIdx.y * 128;
    const int wave = t >> 6, lane = t & 63;
    const int wm   = wave & 1, wn = wave >> 1;
    const int l15  = lane & 15, quad = lane >> 4;

    const int srow = wave * 32 + (lane >> 2);
    const int scol = (lane & 3) * 8;                              // phys chunk
    const int gcol = (((lane & 3) - ((lane >> 3) & 3)) & 3) * 8;  // logical chunk
    const unsigned short* gA = X + (size_t)(m0 + srow) * EMB + gcol;
    const unsigned short* gB = W + (size_t)(n0 + srow) * EMB + gcol;

    const int arot = (l15 >> 1) & 3;
    const int pc   = ((quad + arot) & 3) * 8;

    const floatx4 zero4 = {0.f, 0.f, 0.f, 0.f};
    floatx4 acc[4][4];
    #pragma unroll
    for (int i = 0; i < 4; ++i)
        #pragma unroll
        for (int j = 0; j < 4; ++j) acc[i][j] = zero4;

    for (int k0 = 0; k0 < EMB; k0 += 64) {
        __syncthreads();
        #pragma unroll
        for (int h = 0; h < 2; ++h) {
            async16(gA + k0 + h * 32,                    &As[h][srow * 32 + scol]);
            async16(gA + k0 + h * 32 + (size_t)16 * EMB, &As[h][(srow + 16) * 32 + scol]);
            async16(gB + k0 + h * 32,                    &Bs[h][srow * 32 + scol]);
            async16(gB + k0 + h * 32 + (size_t)16 * EMB, &Bs[h][(srow + 16) * 32 + scol]);
        }
        __syncthreads();

        #pragma unroll
        for (int h = 0; h < 2; ++h) {
            bf16x8 af[4], bfv[4];
            #pragma unroll
            for (int i = 0; i < 4; ++i) {
                af[i]  = *(const bf16x8*)&As[h][(wm * 64 + i * 16 + l15) * 32 + pc];
                bfv[i] = *(const bf16x8*)&Bs[h][(wn * 64 + i * 16 + l15) * 32 + pc];
            }
            #pragma unroll
            for (int mi = 0; mi < 4; ++mi)
                #pragma unroll
                for (int ni = 0; ni < 4; ++ni)
                    acc[mi][ni] = MFMA16(af[mi], bfv[ni], acc[mi][ni]);
        }
    }

    const int bb = m0 >> 11;   // batch (tiles never straddle a batch)
    #pragma unroll
    for (int ni = 0; ni < 4; ++ni) {
        const int gc     = n0 + wn * 64 + ni * 16 + l15;
        const float bias = BIAS[gc];
        const int which  = gc >> 10;          // 0=q 1=k 2=v (uniform per block)
        const int rem    = gc & 1023;
        const int hh     = rem >> 6;
        const int dd     = rem & 63;
        #pragma unroll
        for (int mi = 0; mi < 4; ++mi) {
            const int nseq0 = (m0 & 2047) + wm * 64 + mi * 16 + quad * 4;
            floatx4 v = acc[mi][ni];
            if (which == 2) {
                ushort4 pk;
                pk.x = f2bf(v[0] + bias); pk.y = f2bf(v[1] + bias);
                pk.z = f2bf(v[2] + bias); pk.w = f2bf(v[3] + bias);
                *(ushort4*)&vtb[((size_t)(bb * NUM_HEADS + hh) * HEAD_DIM + dd) * SEQ + nseq0] = pk;
            } else {
                unsigned short* dst = which ? kb : qb;
                const float sc = which ? 1.0f : QSCALE;
                #pragma unroll
                for (int r = 0; r < 4; ++r)
                    dst[((size_t)(bb * NUM_HEADS + hh) * SEQ + (nseq0 + r)) * HEAD_DIM + dd] =
                        f2bf((v[r] + bias) * sc);
            }
        }
    }
}

// ---------------------------------------------------------------------------
// Kernel 2: flash attention on mfma_32x32x16, register-resident P, rot-swizzled
// K/V LDS tiles. Q-tile = 256 rows, 8 waves (512 thr). Counted-vmcnt double
// buffer (round 4). Round-11: tt software-pipeline, HAND-UNROLLED — two named
// floatx16 sA/sB ping-pong; QK(tt+1)'s 4 MFMAs issue between exp2(tt) and
// the pack/dsum/PV VALU block, filling the matrix pipe under the softmax
// VALU (counters: MfmaUtil 34 + VALUBusy 52, alternating not overlapping).
// No lambdas, no conditional assign (round-5's spill cause). Identical FP
// ops in identical order per tile -> bitwise-identical output. setprio only
// around PV (a fence between lookahead-QK and VALU would kill the interleave).
// VGPR headroom: current 64 of 128 cap; +1 floatx16 -> ~85-100. Spill
// sentinel: WRITE_SIZE must stay 16.4MB.
// __launch_bounds__(512,4): VGPR cap 128 (round-2: (512,6)->40 VGPR spill).
// ---------------------------------------------------------------------------
__global__ __launch_bounds__(512, 4)
void attn_kernel(const unsigned short* __restrict__ qb, const unsigned short* __restrict__ kb,
                 const unsigned short* __restrict__ vtb, unsigned short* __restrict__ attnb)
{
    __shared__ unsigned short smem[2][16384];   // 64 KB: K/V double buffer

    const int t    = threadIdx.x;
    const int bh   = blockIdx.x;
    const int q0   = blockIdx.y * 256;
    const int b    = bh >> 4, hh = bh & 15;
    const int wave = t >> 6, lane = t & 63;
    const int l31  = lane & 31, hl = lane >> 5;
    const int srow = lane >> 2;              // 0..15
    const int scol = (lane & 3) * 8;                              // phys chunk
    const int gcol = (((lane & 3) - ((lane >> 3) & 3)) & 3) * 8;  // logical chunk
    const int rrot = (l31 >> 1) & 3;

    const unsigned short* qp = qb  + (size_t)bh * SEQ * HEAD_DIM;
    const unsigned short* kp = kb  + (size_t)bh * SEQ * HEAD_DIM;
    const unsigned short* vp = vtb + (size_t)bh * HEAD_DIM * SEQ;

    // stage K tile [128][64] (two [128][32] halves) + V tile (4 x [64][32]
    // kv-chunks) for kv block starting at kv0n into buffer B: 4 DMA/thread
    auto stage_kv = [&](int kv0n, unsigned short* B) {
        const int kr = wave * 16 + srow;   // 0..127
        async16(kp + (size_t)(kv0n + kr) * 64 + gcol,      &B[kr * 32 + scol]);
        async16(kp + (size_t)(kv0n + kr) * 64 + 32 + gcol, &B[4096 + kr * 32 + scol]);
        const int kk = wave >> 1;          // V: 4 x [64][32] kv-chunks
        #pragma unroll
        for (int j = 0; j < 2; ++j) {
            const int vd = (wave & 1) * 32 + j * 16 + srow;   // 0..63
            async16(vp + (size_t)vd * SEQ + kv0n + kk * 32 + gcol,
                    &B[8192 + kk * 2048 + vd * 32 + scol]);
        }
    };

    // ---- prologue: Q [256][64] -> buf1 (4 DMA), KV(0) -> buf0 (4 DMA) ----
    {
        const int qr = wave * 16 + srow;   // 0..127
        #pragma unroll
        for (int s = 0; s < 2; ++s)
            #pragma unroll
            for (int h = 0; h < 2; ++h)
                async16(qp + (size_t)(q0 + s * 128 + qr) * 64 + h * 32 + gcol,
                        &smem[1][s * 8192 + h * 4096 + qr * 32 + scol]);
        stage_kv(0, smem[0]);
    }
    asm volatile("s_waitcnt vmcnt(4)" ::: "memory");   // Q (oldest 4) landed
    BAR();                                             // all waves' Q landed
    // Q B-frags (32x32x16): n=q=wave*32+l31, k=d=ks*16+hl*8+j — loop-invariant
    bf16x8 qf[4];
    #pragma unroll
    for (int ks = 0; ks < 4; ++ks)
        qf[ks] = *(const bf16x8*)&smem[1][(wave >> 2) * 8192 + (ks >> 1) * 4096 +
                 ((wave & 3) * 32 + l31) * 32 + ((((ks & 1) * 2 + hl) + rrot) & 3) * 8];
    asm volatile("s_waitcnt lgkmcnt(0)" ::: "memory"); // Q-frag reads done
    BAR();                                             // buf1 free for KV(1)

    floatx16 o[2];
    #pragma unroll
    for (int i = 0; i < 16; ++i) { o[0][i] = 0.f; o[1][i] = 0.f; }
    float dsum = 0.f;

    for (int it = 0; it < 16; ++it) {
        const int cur = it & 1;
        // prefetch next K/V tile into the other buffer; its 4 loads stay in
        // flight across both barriers (counted drain below, NOT vmcnt(0))
        if (it < 15) {
            stage_kv((it + 1) * 128, (unsigned short*)smem[cur ^ 1]);
            asm volatile("s_waitcnt vmcnt(4)" ::: "memory");  // KV(it) landed
        } else {
            asm volatile("s_waitcnt vmcnt(0)" ::: "memory");  // last tile
        }
        BAR();   // all waves' KV(it) landed -> buf[cur] readable

        const unsigned short* S = smem[cur];

        // hand-unrolled tt pipeline: exp2(cur) -> issue QK(next) -> SM+PV(cur)
        floatx16 sA, sB;
        QK_TILE(sA, 0);
        {
            float ev[16];
            #pragma unroll
            for (int i = 0; i < 16; ++i) ev[i] = EXP2(sA[i]);
            QK_TILE(sB, 1);
            SM_PV(ev, 0);
        }
        {
            float ev[16];
            #pragma unroll
            for (int i = 0; i < 16; ++i) ev[i] = EXP2(sB[i]);
            QK_TILE(sA, 2);
            SM_PV(ev, 1);
        }
        {
            float ev[16];
            #pragma unroll
            for (int i = 0; i < 16; ++i) ev[i] = EXP2(sA[i]);
            QK_TILE(sB, 3);
            SM_PV(ev, 2);
        }
        {
            float ev[16];
            #pragma unroll
            for (int i = 0; i < 16; ++i) ev[i] = EXP2(sB[i]);
            SM_PV(ev, 3);
        }

        asm volatile("s_waitcnt lgkmcnt(0)" ::: "memory"); // this iter's reads done
        BAR();   // buf[cur] free for iter it+2's prefetch
    }

    // combine hl halves: lane (l31,*) -> full denominator for q_local = l31
    float dtot = dsum + __shfl_xor(dsum, 32);

    // epilogue: O/l -> attn buffer [b, n, hh*64+d] bf16. O row mapping:
    // q_local_in_wave = e + 8g + 4hl; fetch that lane's dtot via uniform shfl.
    #pragma unroll
    for (int g = 0; g < 4; ++g)
        #pragma unroll
        for (int e = 0; e < 4; ++e) {
            const float da  = __shfl(dtot, g * 8 + e);
            const float db  = __shfl(dtot, g * 8 + e + 4);
            const float inv = 1.0f / (hl ? db : da);
            const int  qrow = q0 + wave * 32 + e + g * 8 + hl * 4;
            #pragma unroll
            for (int dt = 0; dt < 2; ++dt)
                attnb[(size_t)(b * SEQ + qrow) * EMB + hh * HEAD_DIM + dt * 32 + l31] =
                    f2bf(o[dt][g * 4 + e] * inv);
        }
}

// ---------------------------------------------------------------------------
// Kernel 3: out = attn @ fc_w^T + fc_b  (all-bf16, rot-swizzled LDS, fp32
// out). Round-10 VERIFIED: round-4 structure with BK=64 (two [128][32]
// halves) — barrier-halving.
// ---------------------------------------------------------------------------
__global__ __launch_bounds__(256, 3)
void proj_kernel(const unsigned short* __restrict__ A, const unsigned short* __restrict__ W,
                 const float* __restrict__ BIAS, float* __restrict__ out)
{
    __shared__ unsigned short As[2][128 * 32];
    __shared__ unsigned short Bs[2][128 * 32];

    const int t    = threadIdx.x;
    const int n0   = blockIdx.x * 128;
    const int m0   = blockIdx.y * 128;
    const int wave = t >> 6, lane = t & 63;
    const int wm   = wave & 1, wn = wave >> 1;
    const int l15  = lane & 15, quad = lane >> 4;

    const int srow = wave * 32 + (lane >> 2);
    const int scol = (lane & 3) * 8;
    const int gcol = (((lane & 3) - ((lane >> 3) & 3)) & 3) * 8;
    const unsigned short* gA = A + (size_t)(m0 + srow) * EMB + gcol;
    const unsigned short* gB = W + (size_t)(n0 + srow) * EMB + gcol;

    const int arot = (l15 >> 1) & 3;
    const int pc   = ((quad + arot) & 3) * 8;

    const floatx4 zero4 = {0.f, 0.f, 0.f, 0.f};
    floatx4 acc[4][4];
    #pragma unroll
    for (int i = 0; i < 4; ++i)
        #pragma unroll
        for (int j = 0; j < 4; ++j) acc[i][j] = zero4;

    for (int k0 = 0; k0 < EMB; k0 += 64) {
        __syncthreads();
        #pragma unroll
        for (int h = 0; h < 2; ++h) {
            async16(gA + k0 + h * 32,                    &As[h][srow * 32 + scol]);
            async16(gA + k0 + h * 32 + (size_t)16 * EMB, &As[h][(srow + 16) * 32 + scol]);
            async16(gB + k0 + h * 32,                    &Bs[h][srow * 32 + scol]);
            async16(gB + k0 + h * 32 + (size_t)16 * EMB, &Bs[h][(srow + 16) * 32 + scol]);
        }
        __syncthreads();

        #pragma unroll
        for (int h = 0; h < 2; ++h) {
            bf16x8 af[4], bfv[4];
            #pragma unroll
            for (int i = 0; i < 4; ++i) {
                af[i]  = *(const bf16x8*)&As[h][(wm * 64 + i * 16 + l15) * 32 + pc];
                bfv[i] = *(const bf16x8*)&Bs[h][(wn * 64 + i * 16 + l15) * 32 + pc];
            }
            #pragma unroll
            for (int mi = 0; mi < 4; ++mi)
                #pragma unroll
                for (int ni = 0; ni < 4; ++ni)
                    acc[mi][ni] = MFMA16(af[mi], bfv[ni], acc[mi][ni]);
        }
    }

    #pragma unroll
    for (int ni = 0; ni < 4; ++ni) {
        const int gc     = n0 + wn * 64 + ni * 16 + l15;
        const float bias = BIAS[gc];
        #pragma unroll
        for (int mi = 0; mi < 4; ++mi) {
            const int gm = m0 + wm * 64 + mi * 16 + quad * 4;
            #pragma unroll
            for (int r = 0; r < 4; ++r)
                out[(size_t)(gm + r) * EMB + gc] = acc[mi][ni][r] + bias;
        }
    }
}

// ---------------------------------------------------------------------------
extern "C" void kernel_launch(void* const* d_in, const int* in_sizes, int n_in,
                              void* d_out, int out_size, void* d_ws, size_t ws_size,
                              hipStream_t stream) {
    (void)in_sizes; (void)n_in; (void)out_size; (void)ws_size;
    const float* x     = (const float*)d_in[0];
    const float* qkv_w = (const float*)d_in[1];
    const float* qkv_b = (const float*)d_in[2];
    const float* fc_w  = (const float*)d_in[3];
    const float* fc_b  = (const float*)d_in[4];
    float* out = (float*)d_out;

    unsigned short* xb    = (unsigned short*)d_ws;        // 8.4M  (also attnb)
    unsigned short* attnb = xb;
    unsigned short* qbuf  = xb    + QKV_ELEMS;
    unsigned short* kbuf  = qbuf  + QKV_ELEMS;
    unsigned short* vtbuf = kbuf  + QKV_ELEMS;
    unsigned short* qwb   = vtbuf + QKV_ELEMS;            // 3.1M
    unsigned short* fwb   = qwb   + 3 * EMB * EMB;        // 1.0M

    convert_kernel<<<dim3((XV4 + QWV4 + FWV4) / 256), 256, 0, stream>>>(
        x, qkv_w, fc_w, xb, qwb, fwb);
    qkv_kernel<<<dim3(24, 64), 256, 0, stream>>>(xb, qwb, qkv_b, qbuf, kbuf, vtbuf);
    attn_kernel<<<dim3(64, 8), 512, 0, stream>>>(qbuf, kbuf, vtbuf, attnb);
    proj_kernel<<<dim3(8, 64), 256, 0, stream>>>(attnb, fwb, fc_b, out);
}

// Round 12
// 251.244 us; speedup vs baseline: 1.0300x; 1.0300x over previous
//
#include <hip/hip_runtime.h>

#define NUM_HEADS 16
#define HEAD_DIM  64
#define EMB       1024
#define SEQ       2048
#define BATCH     4
#define MROWS     (BATCH * SEQ)          // 8192
#define QKV_ELEMS (MROWS * EMB)          // 8388608

typedef __attribute__((ext_vector_type(4)))  float  floatx4;
typedef __attribute__((ext_vector_type(16))) float  floatx16;
typedef __attribute__((ext_vector_type(8)))  __bf16 bf16x8;

__device__ __forceinline__ unsigned short f2bf(float f) {
    unsigned int u = __float_as_uint(f);
    u += 0x7fffu + ((u >> 16) & 1u);
    return (unsigned short)(u >> 16);
}

__device__ __forceinline__ ushort4 pk4(float4 v) {
    return make_ushort4(f2bf(v.x), f2bf(v.y), f2bf(v.z), f2bf(v.w));
}

// pack 4 fp32 -> 4 bf16 (TRUNCATING) in 2 uints via v_perm_b32.
// P feeds BOTH the numerator (P@V) and the denominator (P@ones) from the
// same packed values, so the one-sided truncation bias cancels in O/l.
__device__ __forceinline__ uint2 packbf4t(float a0, float a1, float a2, float a3) {
    uint2 r;
    r.x = __builtin_amdgcn_perm(__float_as_uint(a1), __float_as_uint(a0), 0x07060302u);
    r.y = __builtin_amdgcn_perm(__float_as_uint(a3), __float_as_uint(a2), 0x07060302u);
    return r;
}

__device__ __forceinline__ bf16x8 mk8(uint2 lo, uint2 hi) {
    union { uint4 u; bf16x8 b; } cvt;
    cvt.u = make_uint4(lo.x, lo.y, hi.x, hi.y);
    return cvt.b;
}

#define MFMA16(a, b, c) __builtin_amdgcn_mfma_f32_16x16x32_bf16((a), (b), (c), 0, 0, 0)
#define MFMA32(a, b, c) __builtin_amdgcn_mfma_f32_32x32x16_bf16((a), (b), (c), 0, 0, 0)
#define EXP2(x) __builtin_amdgcn_exp2f(x)

// raw barrier (no compiler-inserted vmcnt(0) drain) + compiler memory fence
#define BAR() asm volatile("s_barrier" ::: "memory")

// async global->LDS, 16B per lane; LDS dest = wave-uniform base + lane*16
__device__ __forceinline__ void async16(const unsigned short* g, unsigned short* l) {
    __builtin_amdgcn_global_load_lds((const __attribute__((address_space(1))) void*)g,
                                     (__attribute__((address_space(3))) void*)l,
                                     16, 0, 0);
}

// Bank-conflict-killing chunk rotation for [N][32] DMA tiles:
// row R's four 16B chunks are stored rotated by (R>>1)&3. Staging lane i
// (R = base + (i>>2), base % 8 == 0) fetches LOGICAL chunk
// ((i&3) - ((i>>3)&3)) & 3; readers use phys chunk (C + ((R>>1)&3)) & 3.

// q scale folded with log2(e): 0.125 * 1.4426950408889634
#define QSCALE 0.18033688011112042f

// ---------------------------------------------------------------------------
// Kernel 0: fp32 -> bf16 conversion of x, qkv_w, fc_w (memory-bound pre-pass)
// ---------------------------------------------------------------------------
#define XV4  2097152   // 8388608/4
#define QWV4 786432    // 3145728/4
#define FWV4 262144    // 1048576/4

__global__ __launch_bounds__(256)
void convert_kernel(const float* __restrict__ x, const float* __restrict__ qw,
                    const float* __restrict__ fw,
                    unsigned short* __restrict__ xb, unsigned short* __restrict__ qwb,
                    unsigned short* __restrict__ fwb)
{
    const size_t i = (size_t)blockIdx.x * 256 + threadIdx.x;   // float4 units
    const float* src; unsigned short* dst; size_t off;
    if (i < XV4)              { src = x;  dst = xb;  off = i; }
    else if (i < XV4 + QWV4)  { src = qw; dst = qwb; off = i - XV4; }
    else                      { src = fw; dst = fwb; off = i - (XV4 + QWV4); }
    float4 v = ((const float4*)src)[off];
    ((ushort4*)dst)[off] = pk4(v);
}

// ---------------------------------------------------------------------------
// Kernel 1: qkv = xb @ qkv_w^T + qkv_b  (all-bf16, rot-swizzled LDS)
// -> Q (scaled,[b,h,n,d]), K ([b,h,n,d]), V^T ([b,h,d,n]); bf16
// Round-10 VERIFIED (+5.7us total): round-4 structure with BK=64 — K-slab
// as TWO [128][32] halves; halves the barrier/drain events (32 -> 16
// iters, m233: drain is ~72% of the 2-phase loop). LDS 32KB, 3 blocks/CU.
// ---------------------------------------------------------------------------
__global__ __launch_bounds__(256, 3)
void qkv_kernel(const unsigned short* __restrict__ X, const unsigned short* __restrict__ W,
                const float* __restrict__ BIAS,
                unsigned short* __restrict__ qb, unsigned short* __restrict__ kb,
                unsigned short* __restrict__ vtb)
{
    __shared__ unsigned short As[2][128 * 32];   // two k-halves, 16 KB
    __shared__ unsigned short Bs[2][128 * 32];   // 16 KB

    const int t    = threadIdx.x;
    const int n0   = blockIdx.x * 128;
    const int m0   = blockIdx.y * 128;
    const int wave = t >> 6, lane = t & 63;
    const int wm   = wave & 1, wn = wave >> 1;
    const int l15  = lane & 15, quad = lane >> 4;

    const int srow = wave * 32 + (lane >> 2);
    const int scol = (lane & 3) * 8;                              // phys chunk
    const int gcol = (((lane & 3) - ((lane >> 3) & 3)) & 3) * 8;  // logical chunk
    const unsigned short* gA = X + (size_t)(m0 + srow) * EMB + gcol;
    const unsigned short* gB = W + (size_t)(n0 + srow) * EMB + gcol;

    const int arot = (l15 >> 1) & 3;
    const int pc   = ((quad + arot) & 3) * 8;

    const floatx4 zero4 = {0.f, 0.f, 0.f, 0.f};
    floatx4 acc[4][4];
    #pragma unroll
    for (int i = 0; i < 4; ++i)
        #pragma unroll
        for (int j = 0; j < 4; ++j) acc[i][j] = zero4;

    for (int k0 = 0; k0 < EMB; k0 += 64) {
        __syncthreads();
        #pragma unroll
        for (int h = 0; h < 2; ++h) {
            async16(gA + k0 + h * 32,                    &As[h][srow * 32 + scol]);
            async16(gA + k0 + h * 32 + (size_t)16 * EMB, &As[h][(srow + 16) * 32 + scol]);
            async16(gB + k0 + h * 32,                    &Bs[h][srow * 32 + scol]);
            async16(gB + k0 + h * 32 + (size_t)16 * EMB, &Bs[h][(srow + 16) * 32 + scol]);
        }
        __syncthreads();

        #pragma unroll
        for (int h = 0; h < 2; ++h) {
            bf16x8 af[4], bfv[4];
            #pragma unroll
            for (int i = 0; i < 4; ++i) {
                af[i]  = *(const bf16x8*)&As[h][(wm * 64 + i * 16 + l15) * 32 + pc];
                bfv[i] = *(const bf16x8*)&Bs[h][(wn * 64 + i * 16 + l15) * 32 + pc];
            }
            #pragma unroll
            for (int mi = 0; mi < 4; ++mi)
                #pragma unroll
                for (int ni = 0; ni < 4; ++ni)
                    acc[mi][ni] = MFMA16(af[mi], bfv[ni], acc[mi][ni]);
        }
    }

    const int bb = m0 >> 11;   // batch (tiles never straddle a batch)
    #pragma unroll
    for (int ni = 0; ni < 4; ++ni) {
        const int gc     = n0 + wn * 64 + ni * 16 + l15;
        const float bias = BIAS[gc];
        const int which  = gc >> 10;          // 0=q 1=k 2=v (uniform per block)
        const int rem    = gc & 1023;
        const int hh     = rem >> 6;
        const int dd     = rem & 63;
        #pragma unroll
        for (int mi = 0; mi < 4; ++mi) {
            const int nseq0 = (m0 & 2047) + wm * 64 + mi * 16 + quad * 4;
            floatx4 v = acc[mi][ni];
            if (which == 2) {
                ushort4 pk;
                pk.x = f2bf(v[0] + bias); pk.y = f2bf(v[1] + bias);
                pk.z = f2bf(v[2] + bias); pk.w = f2bf(v[3] + bias);
                *(ushort4*)&vtb[((size_t)(bb * NUM_HEADS + hh) * HEAD_DIM + dd) * SEQ + nseq0] = pk;
            } else {
                unsigned short* dst = which ? kb : qb;
                const float sc = which ? 1.0f : QSCALE;
                #pragma unroll
                for (int r = 0; r < 4; ++r)
                    dst[((size_t)(bb * NUM_HEADS + hh) * SEQ + (nseq0 + r)) * HEAD_DIM + dd] =
                        f2bf((v[r] + bias) * sc);
            }
        }
    }
}

// ---------------------------------------------------------------------------
// Kernel 2: flash attention on mfma_32x32x16, register-resident P, rot-swizzled
// K/V LDS tiles. Q-tile = 256 rows, 8 waves (512 thr). Counted-vmcnt double
// buffer (round 4, verified).
// Round-12: denominator moved BACK to the MFMA pipe (round-0's verified
// ones-MFMA scheme: o_sum = P @ ones) — the isolated A/B rounds 2->3 never
// ran. Counters across 6 attn experiments: MfmaUtil ~34 + VALUBusy ~52,
// alternating not overlapping. dsum cost 124 VALU ops/iter (~248 cyc);
// ones-MFMA costs 8 MFMA32/iter (~64 cyc on the 34%-busy matrix pipe).
// Serial-pipes model predicts ~-11% attn; if neutral, pipes DO overlap and
// attn is at its structural floor. Epilogue simplifies: o_sum shares o's
// C-row mapping -> in-lane divide, no shfl redistribution.
// Truncating pack feeds BOTH P@V and P@ones -> truncation bias cancels
// (round-0 numerics, absmax 4.88e-4 verified).
// __launch_bounds__(512,4): VGPR cap 128; +16 o_sum -> ~80, no spill
// (sentinel: WRITE_SIZE must stay 16.4MB).
// ---------------------------------------------------------------------------
__global__ __launch_bounds__(512, 4)
void attn_kernel(const unsigned short* __restrict__ qb, const unsigned short* __restrict__ kb,
                 const unsigned short* __restrict__ vtb, unsigned short* __restrict__ attnb)
{
    __shared__ unsigned short smem[2][16384];   // 64 KB: K/V double buffer

    const int t    = threadIdx.x;
    const int bh   = blockIdx.x;
    const int q0   = blockIdx.y * 256;
    const int b    = bh >> 4, hh = bh & 15;
    const int wave = t >> 6, lane = t & 63;
    const int l31  = lane & 31, hl = lane >> 5;
    const int srow = lane >> 2;              // 0..15
    const int scol = (lane & 3) * 8;                              // phys chunk
    const int gcol = (((lane & 3) - ((lane >> 3) & 3)) & 3) * 8;  // logical chunk
    const int rrot = (l31 >> 1) & 3;

    const unsigned short* qp = qb  + (size_t)bh * SEQ * HEAD_DIM;
    const unsigned short* kp = kb  + (size_t)bh * SEQ * HEAD_DIM;
    const unsigned short* vp = vtb + (size_t)bh * HEAD_DIM * SEQ;

    // stage K tile [128][64] (two [128][32] halves) + V tile (4 x [64][32]
    // kv-chunks) for kv block starting at kv0n into buffer B: 4 DMA/thread
    auto stage_kv = [&](int kv0n, unsigned short* B) {
        const int kr = wave * 16 + srow;   // 0..127
        async16(kp + (size_t)(kv0n + kr) * 64 + gcol,      &B[kr * 32 + scol]);
        async16(kp + (size_t)(kv0n + kr) * 64 + 32 + gcol, &B[4096 + kr * 32 + scol]);
        const int kk = wave >> 1;          // V: 4 x [64][32] kv-chunks
        #pragma unroll
        for (int j = 0; j < 2; ++j) {
            const int vd = (wave & 1) * 32 + j * 16 + srow;   // 0..63
            async16(vp + (size_t)vd * SEQ + kv0n + kk * 32 + gcol,
                    &B[8192 + kk * 2048 + vd * 32 + scol]);
        }
    };

    // ---- prologue: Q [256][64] -> buf1 (4 DMA), KV(0) -> buf0 (4 DMA) ----
    {
        const int qr = wave * 16 + srow;   // 0..127
        #pragma unroll
        for (int s = 0; s < 2; ++s)
            #pragma unroll
            for (int h = 0; h < 2; ++h)
                async16(qp + (size_t)(q0 + s * 128 + qr) * 64 + h * 32 + gcol,
                        &smem[1][s * 8192 + h * 4096 + qr * 32 + scol]);
        stage_kv(0, smem[0]);
    }
    asm volatile("s_waitcnt vmcnt(4)" ::: "memory");   // Q (oldest 4) landed
    BAR();                                             // all waves' Q landed
    // Q B-frags (32x32x16): n=q=wave*32+l31, k=d=ks*16+hl*8+j — loop-invariant
    bf16x8 qf[4];
    #pragma unroll
    for (int ks = 0; ks < 4; ++ks)
        qf[ks] = *(const bf16x8*)&smem[1][(wave >> 2) * 8192 + (ks >> 1) * 4096 +
                 ((wave & 3) * 32 + l31) * 32 + ((((ks & 1) * 2 + hl) + rrot) & 3) * 8];
    asm volatile("s_waitcnt lgkmcnt(0)" ::: "memory"); // Q-frag reads done
    BAR();                                             // buf1 free for KV(1)

    bf16x8 ones;
    #pragma unroll
    for (int i = 0; i < 8; ++i) ones[i] = (__bf16)1.0f;

    floatx16 o[2], o_sum;
    #pragma unroll
    for (int i = 0; i < 16; ++i) { o[0][i] = 0.f; o[1][i] = 0.f; o_sum[i] = 0.f; }

    for (int it = 0; it < 16; ++it) {
        const int cur = it & 1;
        // prefetch next K/V tile into the other buffer; its 4 loads stay in
        // flight across both barriers (counted drain below, NOT vmcnt(0))
        if (it < 15) {
            stage_kv((it + 1) * 128, (unsigned short*)smem[cur ^ 1]);
            asm volatile("s_waitcnt vmcnt(4)" ::: "memory");  // KV(it) landed
        } else {
            asm volatile("s_waitcnt vmcnt(0)" ::: "memory");  // last tile
        }
        BAR();   // all waves' KV(it) landed -> buf[cur] readable

        const unsigned short* S = smem[cur];

        #pragma unroll
        for (int tt = 0; tt < 4; ++tt) {        // 32-kv tiles
            // S^T tile: A=K (m=kv=tt*32+l31, k=d), B=Q
            floatx16 st;
            #pragma unroll
            for (int i = 0; i < 16; ++i) st[i] = 0.f;
            __builtin_amdgcn_s_setprio(1);
            #pragma unroll
            for (int ks = 0; ks < 4; ++ks) {
                bf16x8 kf = *(const bf16x8*)&S[(ks >> 1) * 4096 +
                            (tt * 32 + l31) * 32 + ((((ks & 1) * 2 + hl) + rrot) & 3) * 8];
                st = MFMA32(kf, qf[ks], st);
            }
            __builtin_amdgcn_s_setprio(0);

            // exp2 + truncating pack: pk[g] holds kv {8g+4hl..8g+4hl+3}, q=l31
            uint2 pk0 = packbf4t(EXP2(st[0]),  EXP2(st[1]),  EXP2(st[2]),  EXP2(st[3]));
            uint2 pk1 = packbf4t(EXP2(st[4]),  EXP2(st[5]),  EXP2(st[6]),  EXP2(st[7]));
            uint2 pk2 = packbf4t(EXP2(st[8]),  EXP2(st[9]),  EXP2(st[10]), EXP2(st[11]));
            uint2 pk3 = packbf4t(EXP2(st[12]), EXP2(st[13]), EXP2(st[14]), EXP2(st[15]));

            // C->A layout fix via v_permlane32_swap (branch-free):
            //   swap(a,b) -> a' = {a.lo32, b.lo32}, b' = {a.hi32, b.hi32}
            auto sA0 = __builtin_amdgcn_permlane32_swap(pk0.x, pk1.x, false, false);
            auto sA1 = __builtin_amdgcn_permlane32_swap(pk0.y, pk1.y, false, false);
            auto sB0 = __builtin_amdgcn_permlane32_swap(pk2.x, pk3.x, false, false);
            auto sB1 = __builtin_amdgcn_permlane32_swap(pk2.y, pk3.y, false, false);
            bf16x8 pfA = mk8(make_uint2(sA0[0], sA1[0]), make_uint2(sA0[1], sA1[1])); // kv blk tt*2+0
            bf16x8 pfB = mk8(make_uint2(sB0[0], sB1[0]), make_uint2(sB0[1], sB1[1])); // kv blk tt*2+1

            // PV: O[q][d] += P @ V ; denominator on the MFMA pipe: o_sum += P @ ones
            __builtin_amdgcn_s_setprio(1);
            #pragma unroll
            for (int s = 0; s < 2; ++s) {
                const bf16x8 pf = s ? pfB : pfA;
                const int kvblk = tt * 2 + s;                // 16-kv block 0..7
                const int vbase = 8192 + (kvblk >> 1) * 2048;
                const int vchun = ((((kvblk & 1) * 2 + hl) + rrot) & 3) * 8;
                #pragma unroll
                for (int dt = 0; dt < 2; ++dt) {
                    bf16x8 vf = *(const bf16x8*)&S[vbase + (dt * 32 + l31) * 32 + vchun];
                    o[dt] = MFMA32(pf, vf, o[dt]);
                }
                o_sum = MFMA32(pf, ones, o_sum);
            }
            __builtin_amdgcn_s_setprio(0);
        }

        asm volatile("s_waitcnt lgkmcnt(0)" ::: "memory"); // this iter's reads done
        BAR();   // buf[cur] free for iter it+2's prefetch
    }

    // epilogue: O/l -> attn buffer [b, n, hh*64+d] bf16 (denominator in-lane:
    // o and o_sum share the C row mapping q=(e)+8g+4hl, col d=dt*32+l31)
    #pragma unroll
    for (int g = 0; g < 4; ++g)
        #pragma unroll
        for (int e = 0; e < 4; ++e) {
            const float inv  = 1.0f / o_sum[g * 4 + e];
            const int  qrow  = q0 + wave * 32 + e + g * 8 + hl * 4;
            #pragma unroll
            for (int dt = 0; dt < 2; ++dt)
                attnb[(size_t)(b * SEQ + qrow) * EMB + hh * HEAD_DIM + dt * 32 + l31] =
                    f2bf(o[dt][g * 4 + e] * inv);
        }
}

// ---------------------------------------------------------------------------
// Kernel 3: out = attn @ fc_w^T + fc_b  (all-bf16, rot-swizzled LDS, fp32
// out). Round-10 VERIFIED: round-4 structure with BK=64 (two [128][32]
// halves) — barrier-halving.
// ---------------------------------------------------------------------------
__global__ __launch_bounds__(256, 3)
void proj_kernel(const unsigned short* __restrict__ A, const unsigned short* __restrict__ W,
                 const float* __restrict__ BIAS, float* __restrict__ out)
{
    __shared__ unsigned short As[2][128 * 32];
    __shared__ unsigned short Bs[2][128 * 32];

    const int t    = threadIdx.x;
    const int n0   = blockIdx.x * 128;
    const int m0   = blockIdx.y * 128;
    const int wave = t >> 6, lane = t & 63;
    const int wm   = wave & 1, wn = wave >> 1;
    const int l15  = lane & 15, quad = lane >> 4;

    const int srow = wave * 32 + (lane >> 2);
    const int scol = (lane & 3) * 8;
    const int gcol = (((lane & 3) - ((lane >> 3) & 3)) & 3) * 8;
    const unsigned short* gA = A + (size_t)(m0 + srow) * EMB + gcol;
    const unsigned short* gB = W + (size_t)(n0 + srow) * EMB + gcol;

    const int arot = (l15 >> 1) & 3;
    const int pc   = ((quad + arot) & 3) * 8;

    const floatx4 zero4 = {0.f, 0.f, 0.f, 0.f};
    floatx4 acc[4][4];
    #pragma unroll
    for (int i = 0; i < 4; ++i)
        #pragma unroll
        for (int j = 0; j < 4; ++j) acc[i][j] = zero4;

    for (int k0 = 0; k0 < EMB; k0 += 64) {
        __syncthreads();
        #pragma unroll
        for (int h = 0; h < 2; ++h) {
            async16(gA + k0 + h * 32,                    &As[h][srow * 32 + scol]);
            async16(gA + k0 + h * 32 + (size_t)16 * EMB, &As[h][(srow + 16) * 32 + scol]);
            async16(gB + k0 + h * 32,                    &Bs[h][srow * 32 + scol]);
            async16(gB + k0 + h * 32 + (size_t)16 * EMB, &Bs[h][(srow + 16) * 32 + scol]);
        }
        __syncthreads();

        #pragma unroll
        for (int h = 0; h < 2; ++h) {
            bf16x8 af[4], bfv[4];
            #pragma unroll
            for (int i = 0; i < 4; ++i) {
                af[i]  = *(const bf16x8*)&As[h][(wm * 64 + i * 16 + l15) * 32 + pc];
                bfv[i] = *(const bf16x8*)&Bs[h][(wn * 64 + i * 16 + l15) * 32 + pc];
            }
            #pragma unroll
            for (int mi = 0; mi < 4; ++mi)
                #pragma unroll
                for (int ni = 0; ni < 4; ++ni)
                    acc[mi][ni] = MFMA16(af[mi], bfv[ni], acc[mi][ni]);
        }
    }

    #pragma unroll
    for (int ni = 0; ni < 4; ++ni) {
        const int gc     = n0 + wn * 64 + ni * 16 + l15;
        const float bias = BIAS[gc];
        #pragma unroll
        for (int mi = 0; mi < 4; ++mi) {
            const int gm = m0 + wm * 64 + mi * 16 + quad * 4;
            #pragma unroll
            for (int r = 0; r < 4; ++r)
                out[(size_t)(gm + r) * EMB + gc] = acc[mi][ni][r] + bias;
        }
    }
}

// ---------------------------------------------------------------------------
extern "C" void kernel_launch(void* const* d_in, const int* in_sizes, int n_in,
                              void* d_out, int out_size, void* d_ws, size_t ws_size,
                              hipStream_t stream) {
    (void)in_sizes; (void)n_in; (void)out_size; (void)ws_size;
    const float* x     = (const float*)d_in[0];
    const float* qkv_w = (const float*)d_in[1];
    const float* qkv_b = (const float*)d_in[2];
    const float* fc_w  = (const float*)d_in[3];
    const float* fc_b  = (const float*)d_in[4];
    float* out = (float*)d_out;

    unsigned short* xb    = (unsigned short*)d_ws;        // 8.4M  (also attnb)
    unsigned short* attnb = xb;
    unsigned short* qbuf  = xb    + QKV_ELEMS;
    unsigned short* kbuf  = qbuf  + QKV_ELEMS;
    unsigned short* vtbuf = kbuf  + QKV_ELEMS;
    unsigned short* qwb   = vtbuf + QKV_ELEMS;            // 3.1M
    unsigned short* fwb   = qwb   + 3 * EMB * EMB;        // 1.0M

    convert_kernel<<<dim3((XV4 + QWV4 + FWV4) / 256), 256, 0, stream>>>(
        x, qkv_w, fc_w, xb, qwb, fwb);
    qkv_kernel<<<dim3(24, 64), 256, 0, stream>>>(xb, qwb, qkv_b, qbuf, kbuf, vtbuf);
    attn_kernel<<<dim3(64, 8), 512, 0, stream>>>(qbuf, kbuf, vtbuf, attnb);
    proj_kernel<<<dim3(8, 64), 256, 0, stream>>>(attnb, fwb, fc_b, out);
}